// Round 24
// baseline (157.148 us; speedup 1.0000x reference)
//
#include <hip/hip_runtime.h>
#include <hip/hip_bf16.h>
#include <math.h>

typedef __attribute__((ext_vector_type(4))) float f32x4;
typedef __attribute__((ext_vector_type(16))) float f32x16;
typedef __attribute__((ext_vector_type(8))) short bf16x8;
typedef __attribute__((ext_vector_type(4))) unsigned int u32x4;

#define DEV __device__ __forceinline__
#define MFMA16 __builtin_amdgcn_mfma_f32_16x16x32_bf16
#define MFMA32 __builtin_amdgcn_mfma_f32_32x32x16_bf16
#define SBAR __builtin_amdgcn_s_barrier()
#define SCHED0 __builtin_amdgcn_sched_barrier(0)
#define LGKM0 asm volatile("s_waitcnt lgkmcnt(0)" ::: "memory")

constexpr int S      = 2048;
constexpr int DMODEL = 1024;
constexpr int HD     = 64;
constexpr int MROWS  = 4 * 2048;   // B*S = 8192

DEV unsigned short f2bf(float f) {
  union { float f; unsigned int u; } v; v.f = f;
  unsigned int u = v.u;
  unsigned int r = u + 0x7fffu + ((u >> 16) & 1u);
  return (unsigned short)(r >> 16);
}

DEV unsigned int pkbf(float lo, float hi) {
  unsigned int r;
  asm("v_cvt_pk_bf16_f32 %0, %1, %2" : "=v"(r) : "v"(lo), "v"(hi));
  return r;
}

DEV float fexp2(float x) { return __builtin_amdgcn_exp2f(x); }  // raw v_exp_f32

DEV void gload_lds16(const void* g, void* l) {
  __builtin_amdgcn_global_load_lds(
      (const __attribute__((address_space(1))) unsigned int*)g,
      (__attribute__((address_space(3))) unsigned int*)l, 16, 0, 0);
}

// ---------------- merged pre-processing: weight transpose (z<4) + x fp32->bf16 (z>=4) ----------------
__global__ __launch_bounds__(256) void k_pre(const float* __restrict__ x,
                                             const float* __restrict__ Wq,
                                             const float* __restrict__ Wk,
                                             const float* __restrict__ Wv,
                                             const float* __restrict__ Wo,
                                             unsigned short* __restrict__ xb,
                                             unsigned short* __restrict__ wt,
                                             unsigned short* __restrict__ wot) {
  const int z = blockIdx.z;
  if (z < 4) {
    __shared__ float tile[32][33];
    const float* W = (z == 0) ? Wq : (z == 1) ? Wk : (z == 2) ? Wv : Wo;
    unsigned short* Wt = (z == 3) ? wot : wt + (size_t)z * DMODEL * DMODEL;
    int n0 = blockIdx.x * 32, k0 = blockIdx.y * 32;
    int tx = threadIdx.x, ty = threadIdx.y;  // (32,8)
#pragma unroll
    for (int j = 0; j < 4; ++j)
      tile[ty + j * 8][tx] = W[(size_t)(k0 + ty + j * 8) * DMODEL + n0 + tx];
    __syncthreads();
#pragma unroll
    for (int j = 0; j < 4; ++j)
      Wt[(size_t)(n0 + ty + j * 8) * DMODEL + k0 + tx] = f2bf(tile[tx][ty + j * 8]);
  } else {
    int unit = (z - 4) * 1024 + blockIdx.y * 32 + blockIdx.x;
    int tid = threadIdx.y * 32 + threadIdx.x;
    int i = unit * 256 + tid;
    float4 v = ((const float4*)x)[i];
    ushort4 o;
    o.x = f2bf(v.x); o.y = f2bf(v.y); o.z = f2bf(v.z); o.w = f2bf(v.w);
    ((ushort4*)xb)[i] = o;
  }
}

// ---------------- QKV GEMM: 128x192 tile, 4-phase/K-step, 2 blocks/CU (r23 exact) ----------------
__global__ __launch_bounds__(512, 2) void k_gemmQ8(const unsigned short* __restrict__ A,
                                                   const unsigned short* __restrict__ Bt,
                                                   unsigned short* __restrict__ Qg,
                                                   unsigned short* __restrict__ Kg,
                                                   unsigned short* __restrict__ Vt) {
  __shared__ __align__(16) char lds[81920];
  const int tid = threadIdx.x, lane = tid & 63;
  const int wid = tid >> 6, wm = wid >> 2, wn = wid & 3;
  const int lq = lane & 15, lg = lane >> 4;
  constexpr int NBX = 16;                         // N = 3072 / 192
  const int flat = blockIdx.x;                    // 1024 blocks = 2 exact rounds at 2/CU
  const int wg = (flat & 7) * 128 + (flat >> 3);  // bijective XCD swizzle (1024 % 8 == 0)
  const int by = wg / NBX, bx = wg % NBX;
  const int m0 = by * 128, n0 = bx * 192;

  auto stageA = [&](int kt, int unit) {
    char* dA = lds + (kt & 1) * 40960;
    const unsigned short* gA = A + (size_t)m0 * DMODEL + kt * 64;
    int c = tid + unit * 512; int r = c >> 3, cc = c & 7;
    gload_lds16(gA + (size_t)r * DMODEL + ((cc ^ (r & 7)) << 3), dA + c * 16);
  };
  auto stageB = [&](int kt, int unit) {
    char* dB = lds + (kt & 1) * 40960 + 16384;
    const unsigned short* gB = Bt + (size_t)n0 * DMODEL + kt * 64;
    int c = tid + unit * 512; int r = c >> 3, cc = c & 7;
    gload_lds16(gB + (size_t)r * DMODEL + ((cc ^ (r & 7)) << 3), dB + c * 16);
  };

#pragma unroll
  for (int u = 0; u < 2; ++u) stageA(0, u);
#pragma unroll
  for (int u = 0; u < 3; ++u) stageB(0, u);
#pragma unroll
  for (int u = 0; u < 2; ++u) stageA(1, u);
#pragma unroll
  for (int u = 0; u < 3; ++u) stageB(1, u);
  SCHED0;
  asm volatile("s_waitcnt vmcnt(5)" ::: "memory");
  SCHED0;
  SBAR;
  SCHED0;

  f32x4 acc[4][3] = {};
#pragma unroll 1
  for (int t = 0; t < 16; ++t) {
    const char* pA = lds + (t & 1) * 40960;
    const char* pB = pA + 16384;
    const bool sB = (t >= 1 && t <= 14);
    bf16x8 bfr[3];
    // ph0: (kk0, m0..1) + read B kk0 + stage B0,B1(t+1)
    {
      bf16x8 af[2];
#pragma unroll
      for (int mi = 0; mi < 2; ++mi) {
        int row = wm * 64 + mi * 16 + lq;
        af[mi] = *(const bf16x8*)(pA + row * 128 + ((lg ^ (row & 7)) << 4));
      }
#pragma unroll
      for (int ni = 0; ni < 3; ++ni) {
        int row = wn * 48 + ni * 16 + lq;
        bfr[ni] = *(const bf16x8*)(pB + row * 128 + ((lg ^ (row & 7)) << 4));
      }
      if (sB) { stageB(t + 1, 0); stageB(t + 1, 1); }
      SBAR; LGKM0; SCHED0;
      __builtin_amdgcn_s_setprio(1);
#pragma unroll
      for (int mi = 0; mi < 2; ++mi)
#pragma unroll
        for (int ni = 0; ni < 3; ++ni)
          acc[mi][ni] = MFMA16(af[mi], bfr[ni], acc[mi][ni], 0, 0, 0);
      __builtin_amdgcn_s_setprio(0);
      SCHED0;
    }
    // ph1: (kk0, m2..3) + stage B2(t+1)
    {
      bf16x8 af[2];
#pragma unroll
      for (int mi = 0; mi < 2; ++mi) {
        int row = wm * 64 + (mi + 2) * 16 + lq;
        af[mi] = *(const bf16x8*)(pA + row * 128 + ((lg ^ (row & 7)) << 4));
      }
      if (sB) stageB(t + 1, 2);
      SBAR; LGKM0; SCHED0;
      __builtin_amdgcn_s_setprio(1);
#pragma unroll
      for (int mi = 0; mi < 2; ++mi)
#pragma unroll
        for (int ni = 0; ni < 3; ++ni)
          acc[mi + 2][ni] = MFMA16(af[mi], bfr[ni], acc[mi + 2][ni], 0, 0, 0);
      __builtin_amdgcn_s_setprio(0);
      SCHED0;
    }
    // ph2: (kk1, m0..1) + read B kk1
    {
      bf16x8 af[2];
#pragma unroll
      for (int mi = 0; mi < 2; ++mi) {
        int row = wm * 64 + mi * 16 + lq;
        af[mi] = *(const bf16x8*)(pA + row * 128 + (((4 + lg) ^ (row & 7)) << 4));
      }
#pragma unroll
      for (int ni = 0; ni < 3; ++ni) {
        int row = wn * 48 + ni * 16 + lq;
        bfr[ni] = *(const bf16x8*)(pB + row * 128 + (((4 + lg) ^ (row & 7)) << 4));
      }
      SBAR; LGKM0; SCHED0;
      __builtin_amdgcn_s_setprio(1);
#pragma unroll
      for (int mi = 0; mi < 2; ++mi)
#pragma unroll
        for (int ni = 0; ni < 3; ++ni)
          acc[mi][ni] = MFMA16(af[mi], bfr[ni], acc[mi][ni], 0, 0, 0);
      __builtin_amdgcn_s_setprio(0);
      SCHED0;
    }
    // ph3: (kk1, m2..3) + stage A0,A1(t+2)
    {
      bf16x8 af[2];
#pragma unroll
      for (int mi = 0; mi < 2; ++mi) {
        int row = wm * 64 + (mi + 2) * 16 + lq;
        af[mi] = *(const bf16x8*)(pA + row * 128 + (((4 + lg) ^ (row & 7)) << 4));
      }
      if (t < 14) { stageA(t + 2, 0); stageA(t + 2, 1); }
      SBAR; LGKM0; SCHED0;
      __builtin_amdgcn_s_setprio(1);
#pragma unroll
      for (int mi = 0; mi < 2; ++mi)
#pragma unroll
        for (int ni = 0; ni < 3; ++ni)
          acc[mi + 2][ni] = MFMA16(af[mi], bfr[ni], acc[mi + 2][ni], 0, 0, 0);
      __builtin_amdgcn_s_setprio(0);
      SCHED0;
    }
    if (t < 14) {
      asm volatile("s_waitcnt vmcnt(2)" ::: "memory");
    } else if (t == 14) {
      asm volatile("s_waitcnt vmcnt(0)" ::: "memory");
    }
    SCHED0;
    if (t < 15) SBAR;
    SCHED0;
  }

#pragma unroll
  for (int mi = 0; mi < 4; ++mi)
#pragma unroll
    for (int ni = 0; ni < 3; ++ni) {
      int n = n0 + wn * 48 + ni * 16 + lq;
      int widx = n >> 10, nn = n & 1023;
      int h = nn >> 6, d = nn & 63;
      int mbase = m0 + wm * 64 + mi * 16 + lg * 4;
      int b_ = mbase >> 11, s_ = mbase & 2047;
      if (widx == 2) {
        ushort4 o;
        o.x = f2bf(acc[mi][ni][0]);
        o.y = f2bf(acc[mi][ni][1]);
        o.z = f2bf(acc[mi][ni][2]);
        o.w = f2bf(acc[mi][ni][3]);
        *(ushort4*)(Vt + ((size_t)((b_ * 16 + h) * 64 + d)) * S + s_) = o;
      } else {
        unsigned short* dst = (widx == 0) ? Qg : Kg;
        float scale = (widx == 0) ? 0.18033688f : 1.0f;
#pragma unroll
        for (int r = 0; r < 4; ++r)
          dst[(size_t)((b_ * 16 + h) * 2048 + s_ + r) * HD + d] = f2bf(acc[mi][ni][r] * scale);
      }
    }
}

// ---------------- proj GEMM: 128x128 tile, 4-phase/K-step, 2 blocks/CU ----------------
// BM=128, BN=128, BK=64, 512 thr = 8 waves (2M x 4N), per-wave 64x32, acc[4][2].
// LDS: 2 x (A 16K + B 16K) = 64KB -> 2 blocks/CU. Grid 64x8 = 512 = 1 exact round
// at 2/CU capacity. Stage units: A0,A1 + B0,B1 (4/tile); B(t+1) in ph0, A(t+2) in ph3.
// End of K-step: vmcnt(2) drains A(t+1)+B(t+1), keeps A(t+2) flying; prologue vmcnt(4).
// fp32 out = acc + bo[n].
__global__ __launch_bounds__(512, 2) void k_gemmP(const unsigned short* __restrict__ A,
                                                  const unsigned short* __restrict__ Bt,
                                                  const float* __restrict__ bo,
                                                  float* __restrict__ out) {
  __shared__ __align__(16) char lds[65536];
  const int tid = threadIdx.x, lane = tid & 63;
  const int wid = tid >> 6, wm = wid >> 2, wn = wid & 3;
  const int lq = lane & 15, lg = lane >> 4;
  constexpr int NBX = 8;                          // N = 1024 / 128
  const int flat = blockIdx.x;                    // 512 blocks = 1 exact round at 2/CU
  const int wg = (flat & 7) * 64 + (flat >> 3);   // bijective XCD swizzle (512 % 8 == 0)
  const int by = wg / NBX, bx = wg % NBX;
  const int m0 = by * 128, n0 = bx * 128;

  auto stageA = [&](int kt, int unit) {
    char* dA = lds + (kt & 1) * 32768;
    const unsigned short* gA = A + (size_t)m0 * DMODEL + kt * 64;
    int c = tid + unit * 512; int r = c >> 3, cc = c & 7;
    gload_lds16(gA + (size_t)r * DMODEL + ((cc ^ (r & 7)) << 3), dA + c * 16);
  };
  auto stageB = [&](int kt, int unit) {
    char* dB = lds + (kt & 1) * 32768 + 16384;
    const unsigned short* gB = Bt + (size_t)n0 * DMODEL + kt * 64;
    int c = tid + unit * 512; int r = c >> 3, cc = c & 7;
    gload_lds16(gB + (size_t)r * DMODEL + ((cc ^ (r & 7)) << 3), dB + c * 16);
  };

#pragma unroll
  for (int u = 0; u < 2; ++u) stageA(0, u);
#pragma unroll
  for (int u = 0; u < 2; ++u) stageB(0, u);
#pragma unroll
  for (int u = 0; u < 2; ++u) stageA(1, u);
#pragma unroll
  for (int u = 0; u < 2; ++u) stageB(1, u);
  SCHED0;
  asm volatile("s_waitcnt vmcnt(4)" ::: "memory");
  SCHED0;
  SBAR;
  SCHED0;

  f32x4 acc[4][2] = {};
#pragma unroll 1
  for (int t = 0; t < 16; ++t) {
    const char* pA = lds + (t & 1) * 32768;
    const char* pB = pA + 16384;
    const bool sB = (t >= 1 && t <= 14);
    bf16x8 bfr[2];
    // ph0: (kk0, m0..1) + read B kk0 + stage B0,B1(t+1)
    {
      bf16x8 af[2];
#pragma unroll
      for (int mi = 0; mi < 2; ++mi) {
        int row = wm * 64 + mi * 16 + lq;
        af[mi] = *(const bf16x8*)(pA + row * 128 + ((lg ^ (row & 7)) << 4));
      }
#pragma unroll
      for (int ni = 0; ni < 2; ++ni) {
        int row = wn * 32 + ni * 16 + lq;
        bfr[ni] = *(const bf16x8*)(pB + row * 128 + ((lg ^ (row & 7)) << 4));
      }
      if (sB) { stageB(t + 1, 0); stageB(t + 1, 1); }
      SBAR; LGKM0; SCHED0;
      __builtin_amdgcn_s_setprio(1);
#pragma unroll
      for (int mi = 0; mi < 2; ++mi)
#pragma unroll
        for (int ni = 0; ni < 2; ++ni)
          acc[mi][ni] = MFMA16(af[mi], bfr[ni], acc[mi][ni], 0, 0, 0);
      __builtin_amdgcn_s_setprio(0);
      SCHED0;
    }
    // ph1: (kk0, m2..3)
    {
      bf16x8 af[2];
#pragma unroll
      for (int mi = 0; mi < 2; ++mi) {
        int row = wm * 64 + (mi + 2) * 16 + lq;
        af[mi] = *(const bf16x8*)(pA + row * 128 + ((lg ^ (row & 7)) << 4));
      }
      SBAR; LGKM0; SCHED0;
      __builtin_amdgcn_s_setprio(1);
#pragma unroll
      for (int mi = 0; mi < 2; ++mi)
#pragma unroll
        for (int ni = 0; ni < 2; ++ni)
          acc[mi + 2][ni] = MFMA16(af[mi], bfr[ni], acc[mi + 2][ni], 0, 0, 0);
      __builtin_amdgcn_s_setprio(0);
      SCHED0;
    }
    // ph2: (kk1, m0..1) + read B kk1
    {
      bf16x8 af[2];
#pragma unroll
      for (int mi = 0; mi < 2; ++mi) {
        int row = wm * 64 + mi * 16 + lq;
        af[mi] = *(const bf16x8*)(pA + row * 128 + (((4 + lg) ^ (row & 7)) << 4));
      }
#pragma unroll
      for (int ni = 0; ni < 2; ++ni) {
        int row = wn * 32 + ni * 16 + lq;
        bfr[ni] = *(const bf16x8*)(pB + row * 128 + (((4 + lg) ^ (row & 7)) << 4));
      }
      SBAR; LGKM0; SCHED0;
      __builtin_amdgcn_s_setprio(1);
#pragma unroll
      for (int mi = 0; mi < 2; ++mi)
#pragma unroll
        for (int ni = 0; ni < 2; ++ni)
          acc[mi][ni] = MFMA16(af[mi], bfr[ni], acc[mi][ni], 0, 0, 0);
      __builtin_amdgcn_s_setprio(0);
      SCHED0;
    }
    // ph3: (kk1, m2..3) + stage A0,A1(t+2)
    {
      bf16x8 af[2];
#pragma unroll
      for (int mi = 0; mi < 2; ++mi) {
        int row = wm * 64 + (mi + 2) * 16 + lq;
        af[mi] = *(const bf16x8*)(pA + row * 128 + (((4 + lg) ^ (row & 7)) << 4));
      }
      if (t < 14) { stageA(t + 2, 0); stageA(t + 2, 1); }
      SBAR; LGKM0; SCHED0;
      __builtin_amdgcn_s_setprio(1);
#pragma unroll
      for (int mi = 0; mi < 2; ++mi)
#pragma unroll
        for (int ni = 0; ni < 2; ++ni)
          acc[mi + 2][ni] = MFMA16(af[mi], bfr[ni], acc[mi + 2][ni], 0, 0, 0);
      __builtin_amdgcn_s_setprio(0);
      SCHED0;
    }
    if (t < 14) {
      asm volatile("s_waitcnt vmcnt(2)" ::: "memory");
    } else if (t == 14) {
      asm volatile("s_waitcnt vmcnt(0)" ::: "memory");
    }
    SCHED0;
    if (t < 15) SBAR;
    SCHED0;
  }

#pragma unroll
  for (int mi = 0; mi < 4; ++mi)
#pragma unroll
    for (int ni = 0; ni < 2; ++ni) {
      int n = n0 + wn * 32 + ni * 16 + lq;
      float bv = bo[n];
#pragma unroll
      for (int r = 0; r < 4; ++r) {
        int m = m0 + wm * 64 + mi * 16 + lg * 4 + r;
        out[(size_t)m * DMODEL + n] = acc[mi][ni][r] + bv;
      }
    }
}

// ---------------- causal flash attention (r11 exact — the 156-160us config) ----------------
__global__ __launch_bounds__(512, 2) void k_attn(const unsigned short* __restrict__ Qg,
                                                 const unsigned short* __restrict__ Kg,
                                                 const unsigned short* __restrict__ Vt,
                                                 unsigned short* __restrict__ Ctx) {
  __shared__ __align__(16) char lds[32768];
  const int f = blockIdx.x;           // 0..511
  const int i4 = f & 255, hi2 = f >> 8;
  const int bh = i4 >> 2, q = i4 & 3;
  const int Qb = hi2 ? (7 - q) : q;
  const int tid = threadIdx.x;
  const int lane = tid & 63, w = tid >> 6;
  const int lq5 = lane & 31, hi = lane >> 5;
  const size_t base = (size_t)bh * (S * HD);
  const int b = bh >> 4, h = bh & 15;
  const int krow = tid >> 3, kcc = tid & 7, scc = kcc ^ (krow & 7);
  const int vd = tid >> 3;
  const int vfd = (vd & 7) ^ ((vd >> 3) & 7);
  const int vscc = (tid & 7) ^ vfd;
  const unsigned short* VtRow = Vt + (size_t)(bh * 64 + vd) * S;

  const int q0w = Qb * 256 + w * 32;
  const int tmax = 4 * Qb + 3;
  const int diag = q0w >> 6;

  bf16x8 qF[4];
#pragma unroll
  for (int dc = 0; dc < 4; ++dc)
    qF[dc] = *(const bf16x8*)(Qg + base + (size_t)(q0w + lq5) * HD + dc * 16 + hi * 8);

  f32x16 o0 = {}, o1 = {};
  float m_run = -INFINITY, l_run = 0.f;

  gload_lds16(Kg + base + (size_t)krow * HD + scc * 8, lds + tid * 16);
  gload_lds16(VtRow + vscc * 8, lds + 16384 + tid * 16);
  __syncthreads();

#pragma unroll 1
  for (int t = 0; t <= tmax; ++t) {
    const int cur = t & 1, nxt = cur ^ 1;
    char* sK  = lds + cur * 8192;
    char* sVT = lds + 16384 + cur * 8192;
    const bool have_next = (t < tmax);
    if (have_next) {
      gload_lds16(Kg + base + (size_t)((t + 1) * 64 + krow) * HD + scc * 8,
                  lds + nxt * 8192 + tid * 16);
      gload_lds16(VtRow + (t + 1) * 64 + vscc * 8,
                  lds + 16384 + nxt * 8192 + tid * 16);
    }
    const bool active = (t <= diag);
    if (active) {
      const bool isdiag = (t == diag);
      const int nkb = (isdiag && !(q0w & 32)) ? 1 : 2;
      f32x16 st0 = {}, st1 = {};
#pragma unroll
      for (int dc = 0; dc < 4; ++dc) {
        int row = lq5;
        bf16x8 a0 = *(const bf16x8*)(sK + row * 128 + (((2 * dc + hi) ^ (row & 7)) << 4));
        st0 = MFMA32(a0, qF[dc], st0, 0, 0, 0);
      }
      if (nkb == 2) {
#pragma unroll
        for (int dc = 0; dc < 4; ++dc) {
          int row = 32 + lq5;
          bf16x8 a1 = *(const bf16x8*)(sK + row * 128 + (((2 * dc + hi) ^ (row & 7)) << 4));
          st1 = MFMA32(a1, qF[dc], st1, 0, 0, 0);
        }
      }
      if (isdiag) {
        int qo = q0w + lq5 - t * 64;
        if (q0w & 32) {
#pragma unroll
          for (int r = 0; r < 16; ++r) {
            int key = 32 + (r & 3) + 8 * (r >> 2) + 4 * hi;
            st1[r] = (key > qo) ? -INFINITY : st1[r];
          }
        } else {
#pragma unroll
          for (int r = 0; r < 16; ++r) {
            int key = (r & 3) + 8 * (r >> 2) + 4 * hi;
            st0[r] = (key > qo) ? -INFINITY : st0[r];
          }
        }
      }
      float mx = st0[0];
#pragma unroll
      for (int r = 1; r < 16; ++r) mx = fmaxf(mx, st0[r]);
      if (nkb == 2) {
#pragma unroll
        for (int r = 0; r < 16; ++r) mx = fmaxf(mx, st1[r]);
      }
      mx = fmaxf(mx, __shfl_xor(mx, 32));
      bool need = !(mx <= m_run + 8.0f);
      if (__any(need)) {
        float mn = fmaxf(m_run, mx);
        float alpha = fexp2(m_run - mn);
        m_run = mn;
        l_run *= alpha;
#pragma unroll
        for (int r = 0; r < 16; ++r) { o0[r] *= alpha; o1[r] *= alpha; }
      }
      float rs[4] = {0.f, 0.f, 0.f, 0.f};
#pragma unroll
      for (int r = 0; r < 16; ++r) {
        float p = fexp2(st0[r] - m_run);
        st0[r] = p;
        rs[r & 3] += p;
      }
      if (nkb == 2) {
#pragma unroll
        for (int r = 0; r < 16; ++r) {
          float p = fexp2(st1[r] - m_run);
          st1[r] = p;
          rs[r & 3] += p;
        }
      }
      float rsum = (rs[0] + rs[1]) + (rs[2] + rs[3]);
      rsum += __shfl_xor(rsum, 32);
      l_run += rsum;
      {
        unsigned int wv[8];
#pragma unroll
        for (int j = 0; j < 8; ++j) wv[j] = pkbf(st0[2 * j], st0[2 * j + 1]);
        asm("v_permlane32_swap_b32 %0, %1" : "+v"(wv[0]), "+v"(wv[2]));
        asm("v_permlane32_swap_b32 %0, %1" : "+v"(wv[1]), "+v"(wv[3]));
        asm("v_permlane32_swap_b32 %0, %1" : "+v"(wv[4]), "+v"(wv[6]));
        asm("v_permlane32_swap_b32 %0, %1" : "+v"(wv[5]), "+v"(wv[7]));
        union { bf16x8 v; unsigned int u[4]; } fa, fb;
        fa.u[0] = wv[0]; fa.u[1] = wv[1]; fa.u[2] = wv[2]; fa.u[3] = wv[3];
        fb.u[0] = wv[4]; fb.u[1] = wv[5]; fb.u[2] = wv[6]; fb.u[3] = wv[7];
#pragma unroll
        for (int kc = 0; kc < 2; ++kc) {
          bf16x8 bp = kc ? fb.v : fa.v;
          {
            int d = lq5, fd = (d & 7) ^ ((d >> 3) & 7);
            bf16x8 av = *(const bf16x8*)(sVT + d * 128 + (((kc * 2 + hi) ^ fd) << 4));
            o0 = MFMA32(av, bp, o0, 0, 0, 0);
          }
          {
            int d = 32 + lq5, fd = (d & 7) ^ ((d >> 3) & 7);
            bf16x8 av = *(const bf16x8*)(sVT + d * 128 + (((kc * 2 + hi) ^ fd) << 4));
            o1 = MFMA32(av, bp, o1, 0, 0, 0);
          }
        }
      }
      if (nkb == 2) {
        unsigned int wv[8];
#pragma unroll
        for (int j = 0; j < 8; ++j) wv[j] = pkbf(st1[2 * j], st1[2 * j + 1]);
        asm("v_permlane32_swap_b32 %0, %1" : "+v"(wv[0]), "+v"(wv[2]));
        asm("v_permlane32_swap_b32 %0, %1" : "+v"(wv[1]), "+v"(wv[3]));
        asm("v_permlane32_swap_b32 %0, %1" : "+v"(wv[4]), "+v"(wv[6]));
        asm("v_permlane32_swap_b32 %0, %1" : "+v"(wv[5]), "+v"(wv[7]));
        union { bf16x8 v; unsigned int u[4]; } fa, fb;
        fa.u[0] = wv[0]; fa.u[1] = wv[1]; fa.u[2] = wv[2]; fa.u[3] = wv[3];
        fb.u[0] = wv[4]; fb.u[1] = wv[5]; fb.u[2] = wv[6]; fb.u[3] = wv[7];
#pragma unroll
        for (int kc = 0; kc < 2; ++kc) {
          bf16x8 bp = kc ? fb.v : fa.v;
          {
            int d = lq5, fd = (d & 7) ^ ((d >> 3) & 7);
            bf16x8 av = *(const bf16x8*)(sVT + d * 128 + ((((2 + kc) * 2 + hi) ^ fd) << 4));
            o0 = MFMA32(av, bp, o0, 0, 0, 0);
          }
          {
            int d = 32 + lq5, fd = (d & 7) ^ ((d >> 3) & 7);
            bf16x8 av = *(const bf16x8*)(sVT + d * 128 + ((((2 + kc) * 2 + hi) ^ fd) << 4));
            o1 = MFMA32(av, bp, o1, 0, 0, 0);
          }
        }
      }
    }
    __syncthreads();
  }

  __syncthreads();
  {
    float inv = 1.0f / l_run;
    char* slice = lds + w * 4096;
#pragma unroll
    for (int db = 0; db < 2; ++db)
#pragma unroll
      for (int j = 0; j < 8; ++j) {
        int d0 = (j & 1) * 2 + (j >> 1) * 8 + 4 * hi + 32 * db;
        float va = (db ? o1[2 * j] : o0[2 * j]) * inv;
        float vb = (db ? o1[2 * j + 1] : o0[2 * j + 1]) * inv;
        *(unsigned int*)(slice + lq5 * 128 + (((d0 >> 3) ^ (lq5 & 7)) << 4) + (d0 & 7) * 2) =
            pkbf(va, vb);
      }
    asm volatile("s_waitcnt lgkmcnt(0)" ::: "memory");
#pragma unroll
    for (int i = 0; i < 4; ++i) {
      int r = lane >> 1, cc = (lane & 1) * 4 + i;
      u32x4 v = *(const u32x4*)(slice + r * 128 + ((cc ^ (r & 7)) << 4));
      *(u32x4*)(Ctx + (size_t)(b * S + q0w + r) * DMODEL + h * HD + cc * 8) = v;
    }
  }
}

extern "C" void kernel_launch(void* const* d_in, const int* in_sizes, int n_in,
                              void* d_out, int out_size, void* d_ws, size_t ws_size,
                              hipStream_t stream) {
  const float* x  = (const float*)d_in[0];
  const float* Wq = (const float*)d_in[1];
  const float* Wk = (const float*)d_in[2];
  const float* Wv = (const float*)d_in[3];
  const float* Wo = (const float*)d_in[4];
  const float* bo = (const float*)d_in[5];
  float* out = (float*)d_out;

  char* p = (char*)d_ws;
  unsigned short* xb  = (unsigned short*)p; p += (size_t)MROWS * DMODEL * 2;
  unsigned short* wt  = (unsigned short*)p; p += (size_t)3 * DMODEL * DMODEL * 2;
  unsigned short* wot = (unsigned short*)p; p += (size_t)DMODEL * DMODEL * 2;
  unsigned short* qg  = (unsigned short*)p; p += (size_t)MROWS * DMODEL * 2;
  unsigned short* kg  = (unsigned short*)p; p += (size_t)MROWS * DMODEL * 2;
  unsigned short* vt  = (unsigned short*)p; p += (size_t)MROWS * DMODEL * 2;  // Vt[bh][d][key]
  unsigned short* ctx = (unsigned short*)p; p += (size_t)MROWS * DMODEL * 2;

  k_pre<<<dim3(32, 32, 12), dim3(32, 8), 0, stream>>>(x, Wq, Wk, Wv, Wo, xb, wt, wot);
  k_gemmQ8<<<1024, 512, 0, stream>>>(xb, wt, qg, kg, vt);
  k_attn<<<512, 512, 0, stream>>>(qg, kg, vt, ctx);
  k_gemmP<<<512, 512, 0, stream>>>(ctx, wot, bo, out);
}

// Round 25
// 155.950 us; speedup vs baseline: 1.0077x; 1.0077x over previous
//
#include <hip/hip_runtime.h>
#include <hip/hip_bf16.h>
#include <math.h>

typedef __attribute__((ext_vector_type(4))) float f32x4;
typedef __attribute__((ext_vector_type(16))) float f32x16;
typedef __attribute__((ext_vector_type(8))) short bf16x8;
typedef __attribute__((ext_vector_type(4))) unsigned int u32x4;

#define DEV __device__ __forceinline__
#define MFMA16 __builtin_amdgcn_mfma_f32_16x16x32_bf16
#define MFMA32 __builtin_amdgcn_mfma_f32_32x32x16_bf16
#define SBAR __builtin_amdgcn_s_barrier()
#define SCHED0 __builtin_amdgcn_sched_barrier(0)
#define LGKM0 asm volatile("s_waitcnt lgkmcnt(0)" ::: "memory")

constexpr int S      = 2048;
constexpr int DMODEL = 1024;
constexpr int HD     = 64;
constexpr int MROWS  = 4 * 2048;   // B*S = 8192

DEV unsigned short f2bf(float f) {
  union { float f; unsigned int u; } v; v.f = f;
  unsigned int u = v.u;
  unsigned int r = u + 0x7fffu + ((u >> 16) & 1u);
  return (unsigned short)(r >> 16);
}

DEV unsigned int pkbf(float lo, float hi) {
  unsigned int r;
  asm("v_cvt_pk_bf16_f32 %0, %1, %2" : "=v"(r) : "v"(lo), "v"(hi));
  return r;
}

DEV float fexp2(float x) { return __builtin_amdgcn_exp2f(x); }  // raw v_exp_f32

DEV void gload_lds16(const void* g, void* l) {
  __builtin_amdgcn_global_load_lds(
      (const __attribute__((address_space(1))) unsigned int*)g,
      (__attribute__((address_space(3))) unsigned int*)l, 16, 0, 0);
}

// ---------------- merged pre-processing: weight transpose (z<4) + x fp32->bf16 (z>=4) ----------------
__global__ __launch_bounds__(256) void k_pre(const float* __restrict__ x,
                                             const float* __restrict__ Wq,
                                             const float* __restrict__ Wk,
                                             const float* __restrict__ Wv,
                                             const float* __restrict__ Wo,
                                             unsigned short* __restrict__ xb,
                                             unsigned short* __restrict__ wt,
                                             unsigned short* __restrict__ wot) {
  const int z = blockIdx.z;
  if (z < 4) {
    __shared__ float tile[32][33];
    const float* W = (z == 0) ? Wq : (z == 1) ? Wk : (z == 2) ? Wv : Wo;
    unsigned short* Wt = (z == 3) ? wot : wt + (size_t)z * DMODEL * DMODEL;
    int n0 = blockIdx.x * 32, k0 = blockIdx.y * 32;
    int tx = threadIdx.x, ty = threadIdx.y;  // (32,8)
#pragma unroll
    for (int j = 0; j < 4; ++j)
      tile[ty + j * 8][tx] = W[(size_t)(k0 + ty + j * 8) * DMODEL + n0 + tx];
    __syncthreads();
#pragma unroll
    for (int j = 0; j < 4; ++j)
      Wt[(size_t)(n0 + ty + j * 8) * DMODEL + k0 + tx] = f2bf(tile[tx][ty + j * 8]);
  } else {
    int unit = (z - 4) * 1024 + blockIdx.y * 32 + blockIdx.x;
    int tid = threadIdx.y * 32 + threadIdx.x;
    int i = unit * 256 + tid;
    float4 v = ((const float4*)x)[i];
    ushort4 o;
    o.x = f2bf(v.x); o.y = f2bf(v.y); o.z = f2bf(v.z); o.w = f2bf(v.w);
    ((ushort4*)xb)[i] = o;
  }
}

// ---------------- QKV GEMM: 128x192 tile, 4-phase/K-step, 2 blocks/CU (r23 exact) ----------------
__global__ __launch_bounds__(512, 2) void k_gemmQ8(const unsigned short* __restrict__ A,
                                                   const unsigned short* __restrict__ Bt,
                                                   unsigned short* __restrict__ Qg,
                                                   unsigned short* __restrict__ Kg,
                                                   unsigned short* __restrict__ Vt) {
  __shared__ __align__(16) char lds[81920];
  const int tid = threadIdx.x, lane = tid & 63;
  const int wid = tid >> 6, wm = wid >> 2, wn = wid & 3;
  const int lq = lane & 15, lg = lane >> 4;
  constexpr int NBX = 16;                         // N = 3072 / 192
  const int flat = blockIdx.x;                    // 1024 blocks = 2 exact rounds at 2/CU
  const int wg = (flat & 7) * 128 + (flat >> 3);  // bijective XCD swizzle (1024 % 8 == 0)
  const int by = wg / NBX, bx = wg % NBX;
  const int m0 = by * 128, n0 = bx * 192;

  auto stageA = [&](int kt, int unit) {
    char* dA = lds + (kt & 1) * 40960;
    const unsigned short* gA = A + (size_t)m0 * DMODEL + kt * 64;
    int c = tid + unit * 512; int r = c >> 3, cc = c & 7;
    gload_lds16(gA + (size_t)r * DMODEL + ((cc ^ (r & 7)) << 3), dA + c * 16);
  };
  auto stageB = [&](int kt, int unit) {
    char* dB = lds + (kt & 1) * 40960 + 16384;
    const unsigned short* gB = Bt + (size_t)n0 * DMODEL + kt * 64;
    int c = tid + unit * 512; int r = c >> 3, cc = c & 7;
    gload_lds16(gB + (size_t)r * DMODEL + ((cc ^ (r & 7)) << 3), dB + c * 16);
  };

#pragma unroll
  for (int u = 0; u < 2; ++u) stageA(0, u);
#pragma unroll
  for (int u = 0; u < 3; ++u) stageB(0, u);
#pragma unroll
  for (int u = 0; u < 2; ++u) stageA(1, u);
#pragma unroll
  for (int u = 0; u < 3; ++u) stageB(1, u);
  SCHED0;
  asm volatile("s_waitcnt vmcnt(5)" ::: "memory");
  SCHED0;
  SBAR;
  SCHED0;

  f32x4 acc[4][3] = {};
#pragma unroll 1
  for (int t = 0; t < 16; ++t) {
    const char* pA = lds + (t & 1) * 40960;
    const char* pB = pA + 16384;
    const bool sB = (t >= 1 && t <= 14);
    bf16x8 bfr[3];
    // ph0: (kk0, m0..1) + read B kk0 + stage B0,B1(t+1)
    {
      bf16x8 af[2];
#pragma unroll
      for (int mi = 0; mi < 2; ++mi) {
        int row = wm * 64 + mi * 16 + lq;
        af[mi] = *(const bf16x8*)(pA + row * 128 + ((lg ^ (row & 7)) << 4));
      }
#pragma unroll
      for (int ni = 0; ni < 3; ++ni) {
        int row = wn * 48 + ni * 16 + lq;
        bfr[ni] = *(const bf16x8*)(pB + row * 128 + ((lg ^ (row & 7)) << 4));
      }
      if (sB) { stageB(t + 1, 0); stageB(t + 1, 1); }
      SBAR; LGKM0; SCHED0;
      __builtin_amdgcn_s_setprio(1);
#pragma unroll
      for (int mi = 0; mi < 2; ++mi)
#pragma unroll
        for (int ni = 0; ni < 3; ++ni)
          acc[mi][ni] = MFMA16(af[mi], bfr[ni], acc[mi][ni], 0, 0, 0);
      __builtin_amdgcn_s_setprio(0);
      SCHED0;
    }
    // ph1: (kk0, m2..3) + stage B2(t+1)
    {
      bf16x8 af[2];
#pragma unroll
      for (int mi = 0; mi < 2; ++mi) {
        int row = wm * 64 + (mi + 2) * 16 + lq;
        af[mi] = *(const bf16x8*)(pA + row * 128 + ((lg ^ (row & 7)) << 4));
      }
      if (sB) stageB(t + 1, 2);
      SBAR; LGKM0; SCHED0;
      __builtin_amdgcn_s_setprio(1);
#pragma unroll
      for (int mi = 0; mi < 2; ++mi)
#pragma unroll
        for (int ni = 0; ni < 3; ++ni)
          acc[mi + 2][ni] = MFMA16(af[mi], bfr[ni], acc[mi + 2][ni], 0, 0, 0);
      __builtin_amdgcn_s_setprio(0);
      SCHED0;
    }
    // ph2: (kk1, m0..1) + read B kk1
    {
      bf16x8 af[2];
#pragma unroll
      for (int mi = 0; mi < 2; ++mi) {
        int row = wm * 64 + mi * 16 + lq;
        af[mi] = *(const bf16x8*)(pA + row * 128 + (((4 + lg) ^ (row & 7)) << 4));
      }
#pragma unroll
      for (int ni = 0; ni < 3; ++ni) {
        int row = wn * 48 + ni * 16 + lq;
        bfr[ni] = *(const bf16x8*)(pB + row * 128 + (((4 + lg) ^ (row & 7)) << 4));
      }
      SBAR; LGKM0; SCHED0;
      __builtin_amdgcn_s_setprio(1);
#pragma unroll
      for (int mi = 0; mi < 2; ++mi)
#pragma unroll
        for (int ni = 0; ni < 3; ++ni)
          acc[mi][ni] = MFMA16(af[mi], bfr[ni], acc[mi][ni], 0, 0, 0);
      __builtin_amdgcn_s_setprio(0);
      SCHED0;
    }
    // ph3: (kk1, m2..3) + stage A0,A1(t+2)
    {
      bf16x8 af[2];
#pragma unroll
      for (int mi = 0; mi < 2; ++mi) {
        int row = wm * 64 + (mi + 2) * 16 + lq;
        af[mi] = *(const bf16x8*)(pA + row * 128 + (((4 + lg) ^ (row & 7)) << 4));
      }
      if (t < 14) { stageA(t + 2, 0); stageA(t + 2, 1); }
      SBAR; LGKM0; SCHED0;
      __builtin_amdgcn_s_setprio(1);
#pragma unroll
      for (int mi = 0; mi < 2; ++mi)
#pragma unroll
        for (int ni = 0; ni < 3; ++ni)
          acc[mi + 2][ni] = MFMA16(af[mi], bfr[ni], acc[mi + 2][ni], 0, 0, 0);
      __builtin_amdgcn_s_setprio(0);
      SCHED0;
    }
    if (t < 14) {
      asm volatile("s_waitcnt vmcnt(2)" ::: "memory");
    } else if (t == 14) {
      asm volatile("s_waitcnt vmcnt(0)" ::: "memory");
    }
    SCHED0;
    if (t < 15) SBAR;
    SCHED0;
  }

#pragma unroll
  for (int mi = 0; mi < 4; ++mi)
#pragma unroll
    for (int ni = 0; ni < 3; ++ni) {
      int n = n0 + wn * 48 + ni * 16 + lq;
      int widx = n >> 10, nn = n & 1023;
      int h = nn >> 6, d = nn & 63;
      int mbase = m0 + wm * 64 + mi * 16 + lg * 4;
      int b_ = mbase >> 11, s_ = mbase & 2047;
      if (widx == 2) {
        ushort4 o;
        o.x = f2bf(acc[mi][ni][0]);
        o.y = f2bf(acc[mi][ni][1]);
        o.z = f2bf(acc[mi][ni][2]);
        o.w = f2bf(acc[mi][ni][3]);
        *(ushort4*)(Vt + ((size_t)((b_ * 16 + h) * 64 + d)) * S + s_) = o;
      } else {
        unsigned short* dst = (widx == 0) ? Qg : Kg;
        float scale = (widx == 0) ? 0.18033688f : 1.0f;
#pragma unroll
        for (int r = 0; r < 4; ++r)
          dst[(size_t)((b_ * 16 + h) * 2048 + s_ + r) * HD + d] = f2bf(acc[mi][ni][r] * scale);
      }
    }
}

// ---------------- proj GEMM: 128x256 tile, 4-phase/K-step, grid 256 = 1 exact round ----------------
// (r21 exact — part of the 156.4us best config)
__global__ __launch_bounds__(512, 1) void k_gemmP(const unsigned short* __restrict__ A,
                                                  const unsigned short* __restrict__ Bt,
                                                  const float* __restrict__ bo,
                                                  float* __restrict__ out) {
  __shared__ __align__(16) char lds[98304];
  const int tid = threadIdx.x, lane = tid & 63;
  const int wid = tid >> 6, wm = wid >> 2, wn = wid & 3;
  const int lq = lane & 15, lg = lane >> 4;
  constexpr int NBX = 4;                          // N = 1024 / 256
  const int flat = blockIdx.x;                    // 256 blocks = 1 exact round
  const int wg = (flat & 7) * 32 + (flat >> 3);   // bijective XCD swizzle (256 % 8 == 0)
  const int by = wg / NBX, bx = wg % NBX;
  const int m0 = by * 128, n0 = bx * 256;

  auto stageA = [&](int kt, int unit) {
    char* dA = lds + (kt & 1) * 49152;
    const unsigned short* gA = A + (size_t)m0 * DMODEL + kt * 64;
    int c = tid + unit * 512; int r = c >> 3, cc = c & 7;
    gload_lds16(gA + (size_t)r * DMODEL + ((cc ^ (r & 7)) << 3), dA + c * 16);
  };
  auto stageB = [&](int kt, int unit) {
    char* dB = lds + (kt & 1) * 49152 + 16384;
    const unsigned short* gB = Bt + (size_t)n0 * DMODEL + kt * 64;
    int c = tid + unit * 512; int r = c >> 3, cc = c & 7;
    gload_lds16(gB + (size_t)r * DMODEL + ((cc ^ (r & 7)) << 3), dB + c * 16);
  };

#pragma unroll
  for (int u = 0; u < 2; ++u) stageA(0, u);
#pragma unroll
  for (int u = 0; u < 4; ++u) stageB(0, u);
#pragma unroll
  for (int u = 0; u < 2; ++u) stageA(1, u);
#pragma unroll
  for (int u = 0; u < 4; ++u) stageB(1, u);
  SCHED0;
  asm volatile("s_waitcnt vmcnt(6)" ::: "memory");
  SCHED0;
  SBAR;
  SCHED0;

  f32x4 acc[4][4] = {};
#pragma unroll 1
  for (int t = 0; t < 16; ++t) {
    const char* pA = lds + (t & 1) * 49152;
    const char* pB = pA + 16384;
    const bool sB = (t >= 1 && t <= 14);
    bf16x8 af[4];
    // ph0
    {
      bf16x8 bfr[2];
#pragma unroll
      for (int mi = 0; mi < 4; ++mi) {
        int row = wm * 64 + mi * 16 + lq;
        af[mi] = *(const bf16x8*)(pA + row * 128 + ((lg ^ (row & 7)) << 4));
      }
#pragma unroll
      for (int ni = 0; ni < 2; ++ni) {
        int row = wn * 64 + ni * 16 + lq;
        bfr[ni] = *(const bf16x8*)(pB + row * 128 + ((lg ^ (row & 7)) << 4));
      }
      if (sB) { stageB(t + 1, 0); stageB(t + 1, 1); }
      SBAR; LGKM0; SCHED0;
      __builtin_amdgcn_s_setprio(1);
#pragma unroll
      for (int mi = 0; mi < 4; ++mi)
#pragma unroll
        for (int ni = 0; ni < 2; ++ni)
          acc[mi][ni] = MFMA16(af[mi], bfr[ni], acc[mi][ni], 0, 0, 0);
      __builtin_amdgcn_s_setprio(0);
      SCHED0;
    }
    // ph1
    {
      bf16x8 bfr[2];
#pragma unroll
      for (int ni = 0; ni < 2; ++ni) {
        int row = wn * 64 + (ni + 2) * 16 + lq;
        bfr[ni] = *(const bf16x8*)(pB + row * 128 + ((lg ^ (row & 7)) << 4));
      }
      if (sB) { stageB(t + 1, 2); stageB(t + 1, 3); }
      SBAR; LGKM0; SCHED0;
      __builtin_amdgcn_s_setprio(1);
#pragma unroll
      for (int mi = 0; mi < 4; ++mi)
#pragma unroll
        for (int ni = 0; ni < 2; ++ni)
          acc[mi][ni + 2] = MFMA16(af[mi], bfr[ni], acc[mi][ni + 2], 0, 0, 0);
      __builtin_amdgcn_s_setprio(0);
      SCHED0;
    }
    // ph2
    {
      bf16x8 bfr[2];
#pragma unroll
      for (int mi = 0; mi < 4; ++mi) {
        int row = wm * 64 + mi * 16 + lq;
        af[mi] = *(const bf16x8*)(pA + row * 128 + (((4 + lg) ^ (row & 7)) << 4));
      }
#pragma unroll
      for (int ni = 0; ni < 2; ++ni) {
        int row = wn * 64 + ni * 16 + lq;
        bfr[ni] = *(const bf16x8*)(pB + row * 128 + (((4 + lg) ^ (row & 7)) << 4));
      }
      SBAR; LGKM0; SCHED0;
      __builtin_amdgcn_s_setprio(1);
#pragma unroll
      for (int mi = 0; mi < 4; ++mi)
#pragma unroll
        for (int ni = 0; ni < 2; ++ni)
          acc[mi][ni] = MFMA16(af[mi], bfr[ni], acc[mi][ni], 0, 0, 0);
      __builtin_amdgcn_s_setprio(0);
      SCHED0;
    }
    // ph3
    {
      bf16x8 bfr[2];
#pragma unroll
      for (int ni = 0; ni < 2; ++ni) {
        int row = wn * 64 + (ni + 2) * 16 + lq;
        bfr[ni] = *(const bf16x8*)(pB + row * 128 + (((4 + lg) ^ (row & 7)) << 4));
      }
      if (t < 14) { stageA(t + 2, 0); stageA(t + 2, 1); }
      SBAR; LGKM0; SCHED0;
      __builtin_amdgcn_s_setprio(1);
#pragma unroll
      for (int mi = 0; mi < 4; ++mi)
#pragma unroll
        for (int ni = 0; ni < 2; ++ni)
          acc[mi][ni + 2] = MFMA16(af[mi], bfr[ni], acc[mi][ni + 2], 0, 0, 0);
      __builtin_amdgcn_s_setprio(0);
      SCHED0;
    }
    if (t < 14) {
      asm volatile("s_waitcnt vmcnt(2)" ::: "memory");
    } else if (t == 14) {
      asm volatile("s_waitcnt vmcnt(0)" ::: "memory");
    }
    SCHED0;
    if (t < 15) SBAR;
    SCHED0;
  }

#pragma unroll
  for (int mi = 0; mi < 4; ++mi)
#pragma unroll
    for (int ni = 0; ni < 4; ++ni) {
      int n = n0 + wn * 64 + ni * 16 + lq;
      float bv = bo[n];
#pragma unroll
      for (int r = 0; r < 4; ++r) {
        int m = m0 + wm * 64 + mi * 16 + lg * 4 + r;
        out[(size_t)m * DMODEL + n] = acc[mi][ni][r] + bv;
      }
    }
}

// ---------------- causal flash attention (r11 exact — the 156.4us config) ----------------
__global__ __launch_bounds__(512, 2) void k_attn(const unsigned short* __restrict__ Qg,
                                                 const unsigned short* __restrict__ Kg,
                                                 const unsigned short* __restrict__ Vt,
                                                 unsigned short* __restrict__ Ctx) {
  __shared__ __align__(16) char lds[32768];
  const int f = blockIdx.x;           // 0..511
  const int i4 = f & 255, hi2 = f >> 8;
  const int bh = i4 >> 2, q = i4 & 3;
  const int Qb = hi2 ? (7 - q) : q;
  const int tid = threadIdx.x;
  const int lane = tid & 63, w = tid >> 6;
  const int lq5 = lane & 31, hi = lane >> 5;
  const size_t base = (size_t)bh * (S * HD);
  const int b = bh >> 4, h = bh & 15;
  const int krow = tid >> 3, kcc = tid & 7, scc = kcc ^ (krow & 7);
  const int vd = tid >> 3;
  const int vfd = (vd & 7) ^ ((vd >> 3) & 7);
  const int vscc = (tid & 7) ^ vfd;
  const unsigned short* VtRow = Vt + (size_t)(bh * 64 + vd) * S;

  const int q0w = Qb * 256 + w * 32;
  const int tmax = 4 * Qb + 3;
  const int diag = q0w >> 6;

  bf16x8 qF[4];
#pragma unroll
  for (int dc = 0; dc < 4; ++dc)
    qF[dc] = *(const bf16x8*)(Qg + base + (size_t)(q0w + lq5) * HD + dc * 16 + hi * 8);

  f32x16 o0 = {}, o1 = {};
  float m_run = -INFINITY, l_run = 0.f;

  gload_lds16(Kg + base + (size_t)krow * HD + scc * 8, lds + tid * 16);
  gload_lds16(VtRow + vscc * 8, lds + 16384 + tid * 16);
  __syncthreads();

#pragma unroll 1
  for (int t = 0; t <= tmax; ++t) {
    const int cur = t & 1, nxt = cur ^ 1;
    char* sK  = lds + cur * 8192;
    char* sVT = lds + 16384 + cur * 8192;
    const bool have_next = (t < tmax);
    if (have_next) {
      gload_lds16(Kg + base + (size_t)((t + 1) * 64 + krow) * HD + scc * 8,
                  lds + nxt * 8192 + tid * 16);
      gload_lds16(VtRow + (t + 1) * 64 + vscc * 8,
                  lds + 16384 + nxt * 8192 + tid * 16);
    }
    const bool active = (t <= diag);
    if (active) {
      const bool isdiag = (t == diag);
      const int nkb = (isdiag && !(q0w & 32)) ? 1 : 2;
      f32x16 st0 = {}, st1 = {};
#pragma unroll
      for (int dc = 0; dc < 4; ++dc) {
        int row = lq5;
        bf16x8 a0 = *(const bf16x8*)(sK + row * 128 + (((2 * dc + hi) ^ (row & 7)) << 4));
        st0 = MFMA32(a0, qF[dc], st0, 0, 0, 0);
      }
      if (nkb == 2) {
#pragma unroll
        for (int dc = 0; dc < 4; ++dc) {
          int row = 32 + lq5;
          bf16x8 a1 = *(const bf16x8*)(sK + row * 128 + (((2 * dc + hi) ^ (row & 7)) << 4));
          st1 = MFMA32(a1, qF[dc], st1, 0, 0, 0);
        }
      }
      if (isdiag) {
        int qo = q0w + lq5 - t * 64;
        if (q0w & 32) {
#pragma unroll
          for (int r = 0; r < 16; ++r) {
            int key = 32 + (r & 3) + 8 * (r >> 2) + 4 * hi;
            st1[r] = (key > qo) ? -INFINITY : st1[r];
          }
        } else {
#pragma unroll
          for (int r = 0; r < 16; ++r) {
            int key = (r & 3) + 8 * (r >> 2) + 4 * hi;
            st0[r] = (key > qo) ? -INFINITY : st0[r];
          }
        }
      }
      float mx = st0[0];
#pragma unroll
      for (int r = 1; r < 16; ++r) mx = fmaxf(mx, st0[r]);
      if (nkb == 2) {
#pragma unroll
        for (int r = 0; r < 16; ++r) mx = fmaxf(mx, st1[r]);
      }
      mx = fmaxf(mx, __shfl_xor(mx, 32));
      bool need = !(mx <= m_run + 8.0f);
      if (__any(need)) {
        float mn = fmaxf(m_run, mx);
        float alpha = fexp2(m_run - mn);
        m_run = mn;
        l_run *= alpha;
#pragma unroll
        for (int r = 0; r < 16; ++r) { o0[r] *= alpha; o1[r] *= alpha; }
      }
      float rs[4] = {0.f, 0.f, 0.f, 0.f};
#pragma unroll
      for (int r = 0; r < 16; ++r) {
        float p = fexp2(st0[r] - m_run);
        st0[r] = p;
        rs[r & 3] += p;
      }
      if (nkb == 2) {
#pragma unroll
        for (int r = 0; r < 16; ++r) {
          float p = fexp2(st1[r] - m_run);
          st1[r] = p;
          rs[r & 3] += p;
        }
      }
      float rsum = (rs[0] + rs[1]) + (rs[2] + rs[3]);
      rsum += __shfl_xor(rsum, 32);
      l_run += rsum;
      {
        unsigned int wv[8];
#pragma unroll
        for (int j = 0; j < 8; ++j) wv[j] = pkbf(st0[2 * j], st0[2 * j + 1]);
        asm("v_permlane32_swap_b32 %0, %1" : "+v"(wv[0]), "+v"(wv[2]));
        asm("v_permlane32_swap_b32 %0, %1" : "+v"(wv[1]), "+v"(wv[3]));
        asm("v_permlane32_swap_b32 %0, %1" : "+v"(wv[4]), "+v"(wv[6]));
        asm("v_permlane32_swap_b32 %0, %1" : "+v"(wv[5]), "+v"(wv[7]));
        union { bf16x8 v; unsigned int u[4]; } fa, fb;
        fa.u[0] = wv[0]; fa.u[1] = wv[1]; fa.u[2] = wv[2]; fa.u[3] = wv[3];
        fb.u[0] = wv[4]; fb.u[1] = wv[5]; fb.u[2] = wv[6]; fb.u[3] = wv[7];
#pragma unroll
        for (int kc = 0; kc < 2; ++kc) {
          bf16x8 bp = kc ? fb.v : fa.v;
          {
            int d = lq5, fd = (d & 7) ^ ((d >> 3) & 7);
            bf16x8 av = *(const bf16x8*)(sVT + d * 128 + (((kc * 2 + hi) ^ fd) << 4));
            o0 = MFMA32(av, bp, o0, 0, 0, 0);
          }
          {
            int d = 32 + lq5, fd = (d & 7) ^ ((d >> 3) & 7);
            bf16x8 av = *(const bf16x8*)(sVT + d * 128 + (((kc * 2 + hi) ^ fd) << 4));
            o1 = MFMA32(av, bp, o1, 0, 0, 0);
          }
        }
      }
      if (nkb == 2) {
        unsigned int wv[8];
#pragma unroll
        for (int j = 0; j < 8; ++j) wv[j] = pkbf(st1[2 * j], st1[2 * j + 1]);
        asm("v_permlane32_swap_b32 %0, %1" : "+v"(wv[0]), "+v"(wv[2]));
        asm("v_permlane32_swap_b32 %0, %1" : "+v"(wv[1]), "+v"(wv[3]));
        asm("v_permlane32_swap_b32 %0, %1" : "+v"(wv[4]), "+v"(wv[6]));
        asm("v_permlane32_swap_b32 %0, %1" : "+v"(wv[5]), "+v"(wv[7]));
        union { bf16x8 v; unsigned int u[4]; } fa, fb;
        fa.u[0] = wv[0]; fa.u[1] = wv[1]; fa.u[2] = wv[2]; fa.u[3] = wv[3];
        fb.u[0] = wv[4]; fb.u[1] = wv[5]; fb.u[2] = wv[6]; fb.u[3] = wv[7];
#pragma unroll
        for (int kc = 0; kc < 2; ++kc) {
          bf16x8 bp = kc ? fb.v : fa.v;
          {
            int d = lq5, fd = (d & 7) ^ ((d >> 3) & 7);
            bf16x8 av = *(const bf16x8*)(sVT + d * 128 + ((((2 + kc) * 2 + hi) ^ fd) << 4));
            o0 = MFMA32(av, bp, o0, 0, 0, 0);
          }
          {
            int d = 32 + lq5, fd = (d & 7) ^ ((d >> 3) & 7);
            bf16x8 av = *(const bf16x8*)(sVT + d * 128 + ((((2 + kc) * 2 + hi) ^ fd) << 4));
            o1 = MFMA32(av, bp, o1, 0, 0, 0);
          }
        }
      }
    }
    __syncthreads();
  }

  __syncthreads();
  {
    float inv = 1.0f / l_run;
    char* slice = lds + w * 4096;
#pragma unroll
    for (int db = 0; db < 2; ++db)
#pragma unroll
      for (int j = 0; j < 8; ++j) {
        int d0 = (j & 1) * 2 + (j >> 1) * 8 + 4 * hi + 32 * db;
        float va = (db ? o1[2 * j] : o0[2 * j]) * inv;
        float vb = (db ? o1[2 * j + 1] : o0[2 * j + 1]) * inv;
        *(unsigned int*)(slice + lq5 * 128 + (((d0 >> 3) ^ (lq5 & 7)) << 4) + (d0 & 7) * 2) =
            pkbf(va, vb);
      }
    asm volatile("s_waitcnt lgkmcnt(0)" ::: "memory");
#pragma unroll
    for (int i = 0; i < 4; ++i) {
      int r = lane >> 1, cc = (lane & 1) * 4 + i;
      u32x4 v = *(const u32x4*)(slice + r * 128 + ((cc ^ (r & 7)) << 4));
      *(u32x4*)(Ctx + (size_t)(b * S + q0w + r) * DMODEL + h * HD + cc * 8) = v;
    }
  }
}

extern "C" void kernel_launch(void* const* d_in, const int* in_sizes, int n_in,
                              void* d_out, int out_size, void* d_ws, size_t ws_size,
                              hipStream_t stream) {
  const float* x  = (const float*)d_in[0];
  const float* Wq = (const float*)d_in[1];
  const float* Wk = (const float*)d_in[2];
  const float* Wv = (const float*)d_in[3];
  const float* Wo = (const float*)d_in[4];
  const float* bo = (const float*)d_in[5];
  float* out = (float*)d_out;

  char* p = (char*)d_ws;
  unsigned short* xb  = (unsigned short*)p; p += (size_t)MROWS * DMODEL * 2;
  unsigned short* wt  = (unsigned short*)p; p += (size_t)3 * DMODEL * DMODEL * 2;
  unsigned short* wot = (unsigned short*)p; p += (size_t)DMODEL * DMODEL * 2;
  unsigned short* qg  = (unsigned short*)p; p += (size_t)MROWS * DMODEL * 2;
  unsigned short* kg  = (unsigned short*)p; p += (size_t)MROWS * DMODEL * 2;
  unsigned short* vt  = (unsigned short*)p; p += (size_t)MROWS * DMODEL * 2;  // Vt[bh][d][key]
  unsigned short* ctx = (unsigned short*)p; p += (size_t)MROWS * DMODEL * 2;

  k_pre<<<dim3(32, 32, 12), dim3(32, 8), 0, stream>>>(x, Wq, Wk, Wv, Wo, xb, wt, wot);
  k_gemmQ8<<<1024, 512, 0, stream>>>(xb, wt, qg, kg, vt);
  k_attn<<<512, 512, 0, stream>>>(qg, kg, vt, ctx);
  k_gemmP<<<256, 512, 0, stream>>>(ctx, wot, bo, out);
}